// Round 1
// baseline (395.433 us; speedup 1.0000x reference)
//
#include <hip/hip_runtime.h>
#include <hip/hip_bf16.h>
#include <math.h>

#define N 2048
#define D 32
#define R 64
#define TI 4
#define TJ 64

// (1/sqrt(d)) * log2(e): exp(q*k/sqrt(d)) == exp2((q*scale)*k)
#define INV_SQRT_D_LOG2E (0.17677669529663687f * 1.4426950408889634f)
#define LOG2E 1.4426950408889634f

// ---------------------------------------------------------------- K1: QKV + phi
__global__ __launch_bounds__(128) void qkv_phi_kernel(
    const float* __restrict__ Z,
    const float* __restrict__ Wq, const float* __restrict__ bq,
    const float* __restrict__ Wk, const float* __restrict__ bk,
    const float* __restrict__ Wv, const float* __restrict__ bv,
    const float* __restrict__ omega,
    float* __restrict__ Qg, float* __restrict__ Kg, float* __restrict__ Vg,
    float* __restrict__ phiQ, float* __restrict__ phiK)
{
    __shared__ float Zr[D];
    __shared__ float Qr[D];
    __shared__ float Kr[D];
    const int i = blockIdx.x;
    const int t = threadIdx.x;
    if (t < D) Zr[t] = Z[i * D + t];
    __syncthreads();
    if (t < 96) {
        const int which = t >> 5;
        const int c = t & 31;
        const float* W = (which == 0) ? Wq : (which == 1) ? Wk : Wv;
        const float* b = (which == 0) ? bq : (which == 1) ? bk : bv;
        float acc = b[c];
        #pragma unroll
        for (int k = 0; k < D; ++k) acc += Zr[k] * W[k * D + c];
        if (which == 0)      { Qg[i * D + c] = acc; Qr[c] = acc; }
        else if (which == 1) { Kg[i * D + c] = acc; Kr[c] = acc; }
        else                 { Vg[i * D + c] = acc; }
    }
    __syncthreads();
    // phi: t<64 -> phiQ[r=t], t>=64 -> phiK[r=t-64]
    {
        const float* src = (t < 64) ? Qr : Kr;
        float ssq = 0.f;
        #pragma unroll
        for (int k = 0; k < D; ++k) ssq += src[k] * src[k];
        const float inv = 1.0f / fmaxf(sqrtf(ssq), 1e-6f);
        const int r = t & 63;
        float dot = 0.f;
        #pragma unroll
        for (int k = 0; k < D; ++k) dot += src[k] * omega[k * R + r];
        const float ph = exp2f(dot * inv * LOG2E) * 0.125f; // 1/sqrt(64)
        if (t < 64) phiQ[i * R + r] = ph;
        else        phiK[i * R + r] = ph;
    }
}

// ---------------------------------------------------------------- K2: kv = phiK^T @ V  [R x D]
__global__ __launch_bounds__(256) void kv_kernel(
    const float* __restrict__ phiK, const float* __restrict__ Vg,
    float* __restrict__ kv)
{
    const int e = blockIdx.x * 256 + threadIdx.x; // 0..2047
    const int r = e >> 5, c = e & 31;
    float a0 = 0.f, a1 = 0.f, a2 = 0.f, a3 = 0.f;
    for (int n = 0; n < N; n += 8) {
        a0 += phiK[(n + 0) * R + r] * Vg[(n + 0) * D + c];
        a1 += phiK[(n + 1) * R + r] * Vg[(n + 1) * D + c];
        a2 += phiK[(n + 2) * R + r] * Vg[(n + 2) * D + c];
        a3 += phiK[(n + 3) * R + r] * Vg[(n + 3) * D + c];
        a0 += phiK[(n + 4) * R + r] * Vg[(n + 4) * D + c];
        a1 += phiK[(n + 5) * R + r] * Vg[(n + 5) * D + c];
        a2 += phiK[(n + 6) * R + r] * Vg[(n + 6) * D + c];
        a3 += phiK[(n + 7) * R + r] * Vg[(n + 7) * D + c];
    }
    kv[r * D + c] = (a0 + a1) + (a2 + a3);
}

// ---------------------------------------------------------------- K3: fused scores + S@V + low_rank
__global__ __launch_bounds__(256) void attn_kernel(
    const float* __restrict__ Qg, const float* __restrict__ Kg,
    const float* __restrict__ Vg,
    const float* __restrict__ phiQ, const float* __restrict__ phiK,
    const float* __restrict__ kv, const int* __restrict__ mask,
    float* __restrict__ attn)
{
    __shared__ float qs[TI][D];    // Q rows pre-scaled by s*log2e
    __shared__ float pq[TI][R];
    __shared__ float kvs[R * D];
    __shared__ float S[TI][TJ];
    const int t = threadIdx.x;
    const int row0 = blockIdx.x * TI;

    if (t < TI * D) {
        const int i = t / D, c = t % D;
        qs[i][c] = Qg[(row0 + i) * D + c] * INV_SQRT_D_LOG2E;
    }
    {
        const int i = t >> 6, r = t & 63;
        pq[i][r] = phiQ[(row0 + i) * R + r];
    }
    #pragma unroll
    for (int u = 0; u < 8; ++u) kvs[t + u * 256] = kv[t + u * 256];
    __syncthreads();

    const int i  = t >> 6;        // phase-1 row 0..3 (one per wave)
    const int jl = t & 63;        // phase-1 j within tile
    const int pc = t & 31;        // phase-2 col
    const int pi = (t >> 5) & 3;  // phase-2 row (valid for t<128)
    float acc = 0.f;

    for (int tile = 0; tile < N / TJ; ++tile) {
        const int j = tile * TJ + jl;
        // ---- phase 1: one score per thread
        {
            float esum = 0.f;
            const float4* K4 = (const float4*)(Kg + (size_t)j * D);
            #pragma unroll
            for (int q = 0; q < 8; ++q) {
                const float4 kk = K4[q];
                esum += exp2f(qs[i][4 * q + 0] * kk.x);
                esum += exp2f(qs[i][4 * q + 1] * kk.y);
                esum += exp2f(qs[i][4 * q + 2] * kk.z);
                esum += exp2f(qs[i][4 * q + 3] * kk.w);
            }
            float p = 0.f;
            const float4* P4 = (const float4*)(phiK + (size_t)j * R);
            #pragma unroll
            for (int q = 0; q < 16; ++q) {
                const float4 pk = P4[q];
                p += pq[i][4 * q + 0] * pk.x + pq[i][4 * q + 1] * pk.y
                   + pq[i][4 * q + 2] * pk.z + pq[i][4 * q + 3] * pk.w;
            }
            const int m = mask[(size_t)(row0 + i) * N + j];
            S[i][jl] = (m == 0) ? (esum - p) : 0.f;
        }
        __syncthreads();
        // ---- phase 2: accumulate S @ V (threads 0..127: (pi, pc))
        if (t < TI * D) {
            const float* Vt = Vg + (size_t)tile * TJ * D;
            #pragma unroll
            for (int jj = 0; jj < TJ; ++jj)
                acc += S[pi][jj] * Vt[jj * D + pc];
        }
        __syncthreads();
    }

    if (t < TI * D) {
        float lr = 0.f;
        #pragma unroll
        for (int r = 0; r < R; ++r) lr += pq[pi][r] * kvs[r * D + pc];
        attn[(row0 + pi) * D + pc] = acc + lr;
    }
}

// ---------------------------------------------------------------- K4: epilogue (denom, Wo, LN1, FFN, LN2)
__global__ __launch_bounds__(64) void epilogue_kernel(
    const float* __restrict__ attn, const float* __restrict__ Z,
    const float* __restrict__ Wo, const float* __restrict__ bo,
    const float* __restrict__ W1, const float* __restrict__ b1,
    const float* __restrict__ W2, const float* __restrict__ b2,
    const float* __restrict__ g1, const float* __restrict__ beta1,
    const float* __restrict__ g2, const float* __restrict__ beta2,
    float* __restrict__ out)
{
    const int i = blockIdx.x;
    const int lane = threadIdx.x;
    const int c = lane & 31;            // duplicated across wave halves

    float a = attn[i * D + c];
    // row sum (32) via butterfly within each 32-half (halves are duplicates)
    float s = a;
    s += __shfl_xor(s, 1); s += __shfl_xor(s, 2); s += __shfl_xor(s, 4);
    s += __shfl_xor(s, 8); s += __shfl_xor(s, 16);
    const float an = a / fmaxf(s, 1e-6f);

    // o = an @ Wo + bo
    float o = bo[c];
    #pragma unroll
    for (int k = 0; k < D; ++k) o += __shfl(an, k) * Wo[k * D + c];

    float x = Z[i * D + c] + o;
    // LN1
    float mu = x;
    mu += __shfl_xor(mu, 1); mu += __shfl_xor(mu, 2); mu += __shfl_xor(mu, 4);
    mu += __shfl_xor(mu, 8); mu += __shfl_xor(mu, 16);
    mu *= (1.0f / D);
    const float diff = x - mu;
    float var = diff * diff;
    var += __shfl_xor(var, 1); var += __shfl_xor(var, 2); var += __shfl_xor(var, 4);
    var += __shfl_xor(var, 8); var += __shfl_xor(var, 16);
    var *= (1.0f / D);
    const float z1 = diff * rsqrtf(var + 1e-5f) * g1[c] + beta1[c];

    // FFN hidden: lane -> j0=lane, j1=lane+64 (128 outputs over 64 lanes)
    const int j0 = lane, j1 = lane + 64;
    float h0 = b1[j0], h1 = b1[j1];
    #pragma unroll
    for (int k = 0; k < D; ++k) {
        const float zk = __shfl(z1, k);
        h0 += zk * W1[k * 128 + j0];
        h1 += zk * W1[k * 128 + j1];
    }
    h0 = fmaxf(h0, 0.f); h1 = fmaxf(h1, 0.f);

    float y = b2[c];
    #pragma unroll
    for (int j = 0; j < 64; ++j) {
        y += __shfl(h0, j) * W2[j * D + c];
        y += __shfl(h1, j) * W2[(j + 64) * D + c];
    }

    const float x2 = z1 + y;
    // LN2
    float mu2 = x2;
    mu2 += __shfl_xor(mu2, 1); mu2 += __shfl_xor(mu2, 2); mu2 += __shfl_xor(mu2, 4);
    mu2 += __shfl_xor(mu2, 8); mu2 += __shfl_xor(mu2, 16);
    mu2 *= (1.0f / D);
    const float d2 = x2 - mu2;
    float v2 = d2 * d2;
    v2 += __shfl_xor(v2, 1); v2 += __shfl_xor(v2, 2); v2 += __shfl_xor(v2, 4);
    v2 += __shfl_xor(v2, 8); v2 += __shfl_xor(v2, 16);
    v2 *= (1.0f / D);
    const float res = d2 * rsqrtf(v2 + 1e-5f) * g2[c] + beta2[c];

    if (lane < 32) out[i * D + c] = res;
}

// ----------------------------------------------------------------
extern "C" void kernel_launch(void* const* d_in, const int* in_sizes, int n_in,
                              void* d_out, int out_size, void* d_ws, size_t ws_size,
                              hipStream_t stream) {
    const float* Z     = (const float*)d_in[0];
    const int*   mask  = (const int*)d_in[1];
    const float* Wq    = (const float*)d_in[2];
    const float* bq    = (const float*)d_in[3];
    const float* Wk    = (const float*)d_in[4];
    const float* bk    = (const float*)d_in[5];
    const float* Wv    = (const float*)d_in[6];
    const float* bv    = (const float*)d_in[7];
    const float* Wo    = (const float*)d_in[8];
    const float* bo    = (const float*)d_in[9];
    const float* W1    = (const float*)d_in[10];
    const float* b1    = (const float*)d_in[11];
    const float* W2    = (const float*)d_in[12];
    const float* b2    = (const float*)d_in[13];
    const float* g1    = (const float*)d_in[14];
    const float* be1   = (const float*)d_in[15];
    const float* g2    = (const float*)d_in[16];
    const float* be2   = (const float*)d_in[17];
    const float* omega = (const float*)d_in[18];
    float* out = (float*)d_out;

    float* Qw    = (float*)d_ws;          // N*D
    float* Kw    = Qw + N * D;            // N*D
    float* Vw    = Kw + N * D;            // N*D
    float* pQ    = Vw + N * D;            // N*R
    float* pK    = pQ + N * R;            // N*R
    float* kvw   = pK + N * R;            // R*D
    float* attnw = kvw + R * D;           // N*D

    qkv_phi_kernel<<<N, 128, 0, stream>>>(Z, Wq, bq, Wk, bk, Wv, bv, omega,
                                          Qw, Kw, Vw, pQ, pK);
    kv_kernel<<<(R * D) / 256, 256, 0, stream>>>(pK, Vw, kvw);
    attn_kernel<<<N / TI, 256, 0, stream>>>(Qw, Kw, Vw, pQ, pK, kvw, mask, attnw);
    epilogue_kernel<<<N, 64, 0, stream>>>(attnw, Z, Wo, bo, W1, b1, W2, b2,
                                          g1, be1, g2, be2, out);
}

// Round 2
// 175.665 us; speedup vs baseline: 2.2511x; 2.2511x over previous
//
#include <hip/hip_runtime.h>
#include <hip/hip_bf16.h>
#include <math.h>

#define N 2048
#define D 32
#define R 64
#define TI 8            // rows per attn block
#define JS 8            // j-splits
#define JT (N / JS)     // 256 j's per block

// (1/sqrt(d)) * log2(e): exp(q*k/sqrt(d)) == exp2(q * (k*SCL))
#define SCL (0.17677669529663687f * 1.4426950408889634f)
#define LOG2E 1.4426950408889634f

static __device__ __forceinline__ float fexp2(float x) {
    return __builtin_amdgcn_exp2f(x);
}

// ---------------------------------------------------------------- K1: QKV + phi (4 rows/block)
__global__ __launch_bounds__(128) void qkv_phi_kernel(
    const float* __restrict__ Z,
    const float* __restrict__ Wq, const float* __restrict__ bq,
    const float* __restrict__ Wk, const float* __restrict__ bk,
    const float* __restrict__ Wv, const float* __restrict__ bv,
    const float* __restrict__ omega,
    float* __restrict__ Qg, float* __restrict__ Kg, float* __restrict__ Vg,
    float* __restrict__ phiQ, float* __restrict__ phiK)
{
    __shared__ float Zs[4][D];
    __shared__ float Qn[4][D];
    __shared__ float Kn[4][D];
    const int t = threadIdx.x;
    const int row0 = blockIdx.x * 4;

    Zs[t >> 5][t & 31] = Z[row0 * D + t];
    __syncthreads();

    const int ri = t >> 5;       // 0..3
    const int c  = t & 31;
    float q = bq[c], k = bk[c], v = bv[c];
    #pragma unroll
    for (int kk = 0; kk < D; ++kk) {
        const float z = Zs[ri][kk];
        q += z * Wq[kk * D + c];
        k += z * Wk[kk * D + c];
        v += z * Wv[kk * D + c];
    }
    Qg[(row0 + ri) * D + c] = q;
    Kg[(row0 + ri) * D + c] = k;
    Vg[(row0 + ri) * D + c] = v;

    // row norms (32-lane butterfly; wave halves are distinct rows, masks<32 stay in-half)
    float sq = q * q, sk = k * k;
    #pragma unroll
    for (int m = 1; m <= 16; m <<= 1) { sq += __shfl_xor(sq, m); sk += __shfl_xor(sk, m); }
    const float invq = 1.0f / fmaxf(sqrtf(sq), 1e-6f);
    const float invk = 1.0f / fmaxf(sqrtf(sk), 1e-6f);
    Qn[ri][c] = q * invq;
    Kn[ri][c] = k * invk;
    __syncthreads();

    #pragma unroll
    for (int rep = 0; rep < 2; ++rep) {
        const int idx = t + 128 * rep;
        const int pi = idx >> 6;      // 0..3
        const int r  = idx & 63;
        float dq = 0.f, dk = 0.f;
        #pragma unroll
        for (int kk = 0; kk < D; ++kk) {
            const float o = omega[kk * R + r];
            dq += Qn[pi][kk] * o;
            dk += Kn[pi][kk] * o;
        }
        phiQ[(row0 + pi) * R + r] = fexp2(dq * LOG2E) * 0.125f;
        phiK[(row0 + pi) * R + r] = fexp2(dk * LOG2E) * 0.125f;
    }
}

// ---------------------------------------------------------------- K2: kv += phiK^T @ V (atomic partials)
__global__ __launch_bounds__(256) void kv_kernel(
    const float* __restrict__ phiK, const float* __restrict__ Vg,
    float* __restrict__ kv)
{
    const int n0 = blockIdx.x * 32;
    const int t  = threadIdx.x;
    const int c  = t & 31;
    const int r0 = t >> 5;           // 0..7
    float acc[8];
    #pragma unroll
    for (int k = 0; k < 8; ++k) acc[k] = 0.f;
    for (int n = n0; n < n0 + 32; ++n) {
        const float vv = Vg[n * D + c];
        #pragma unroll
        for (int k = 0; k < 8; ++k)
            acc[k] += phiK[n * R + r0 + 8 * k] * vv;
    }
    #pragma unroll
    for (int k = 0; k < 8; ++k)
        atomicAdd(&kv[(r0 + 8 * k) * D + c], acc[k]);
}

// ---------------------------------------------------------------- K3: scores + S@V partials
__global__ __launch_bounds__(256, 6) void attn_kernel(
    const float* __restrict__ Qg, const float* __restrict__ Kg,
    const float* __restrict__ Vg,
    const float* __restrict__ phiQ, const float* __restrict__ phiK,
    const int* __restrict__ mask,
    float* __restrict__ part)        // [JS][N][D]
{
    __shared__ float S[TI][JT];      // 8 KB
    const int t     = threadIdx.x;
    const int rg    = blockIdx.x / JS;
    const int js    = blockIdx.x % JS;
    const int row0  = rg * TI;
    const int jbase = js * JT;
    const int j     = jbase + t;

    // ---------- phase 1: this thread's column j vs all TI rows
    float esum[TI], pdot[TI];
    #pragma unroll
    for (int i = 0; i < TI; ++i) { esum[i] = 0.f; pdot[i] = 0.f; }

    const float4* K4 = (const float4*)(Kg + (size_t)j * D);
    #pragma unroll
    for (int qc = 0; qc < 8; ++qc) {
        float4 kk = K4[qc];
        kk.x *= SCL; kk.y *= SCL; kk.z *= SCL; kk.w *= SCL;
        #pragma unroll
        for (int i = 0; i < TI; ++i) {
            // wave-uniform address -> scalar load
            const float4 qv = *(const float4*)(Qg + (size_t)(row0 + i) * D + qc * 4);
            esum[i] += fexp2(qv.x * kk.x) + fexp2(qv.y * kk.y)
                     + fexp2(qv.z * kk.z) + fexp2(qv.w * kk.w);
        }
    }
    const float4* P4 = (const float4*)(phiK + (size_t)j * R);
    #pragma unroll
    for (int qc = 0; qc < 16; ++qc) {
        const float4 pk = P4[qc];
        #pragma unroll
        for (int i = 0; i < TI; ++i) {
            const float4 pv = *(const float4*)(phiQ + (size_t)(row0 + i) * R + qc * 4);
            pdot[i] += pv.x * pk.x + pv.y * pk.y + pv.z * pk.z + pv.w * pk.w;
        }
    }
    #pragma unroll
    for (int i = 0; i < TI; ++i) {
        const int m = mask[(size_t)(row0 + i) * N + j];
        S[i][t] = (m == 0) ? (esum[i] - pdot[i]) : 0.f;
    }
    __syncthreads();

    // ---------- phase 2: partial S @ V, one output (i,c) per thread
    const int i = t >> 5;
    const int c = t & 31;
    float acc = 0.f;
    const float* Vt = Vg + (size_t)jbase * D + c;
    const float4* S4 = (const float4*)(&S[i][0]);
    #pragma unroll 8
    for (int jj = 0; jj < JT; jj += 4) {
        const float4 s4 = S4[jj >> 2];
        acc += s4.x * Vt[(jj + 0) * D];
        acc += s4.y * Vt[(jj + 1) * D];
        acc += s4.z * Vt[(jj + 2) * D];
        acc += s4.w * Vt[(jj + 3) * D];
    }
    part[((size_t)js * N + row0 + i) * D + c] = acc;
}

// ---------------------------------------------------------------- K4: epilogue (reduce + lr + denom + Wo + LN + FFN + LN)
__global__ __launch_bounds__(256) void epilogue_kernel(
    const float* __restrict__ part, const float* __restrict__ phiQ,
    const float* __restrict__ kv,   const float* __restrict__ Z,
    const float* __restrict__ Wo, const float* __restrict__ bo,
    const float* __restrict__ W1, const float* __restrict__ b1,
    const float* __restrict__ W2, const float* __restrict__ b2,
    const float* __restrict__ g1, const float* __restrict__ beta1,
    const float* __restrict__ g2, const float* __restrict__ beta2,
    float* __restrict__ out)
{
    const int i    = blockIdx.x * 4 + (threadIdx.x >> 6);  // one row per wave
    const int lane = threadIdx.x & 63;
    const int c    = lane & 31;

    // reduce S@V partials
    float a = 0.f;
    #pragma unroll
    for (int s = 0; s < JS; ++s) a += part[((size_t)s * N + i) * D + c];

    // low rank: phiQ[i] . kv[:, c]
    const float phi_r = phiQ[i * R + lane];
    float lr = 0.f;
    #pragma unroll
    for (int r = 0; r < R; ++r) lr += __shfl(phi_r, r) * kv[r * D + c];
    a += lr;

    // denom
    float s = a;
    #pragma unroll
    for (int m = 1; m <= 16; m <<= 1) s += __shfl_xor(s, m);
    const float an = a / fmaxf(s, 1e-6f);

    // Wo
    float o = bo[c];
    #pragma unroll
    for (int k = 0; k < D; ++k) o += __shfl(an, k) * Wo[k * D + c];

    float x = Z[i * D + c] + o;
    // LN1
    float mu = x;
    #pragma unroll
    for (int m = 1; m <= 16; m <<= 1) mu += __shfl_xor(mu, m);
    mu *= (1.0f / D);
    const float diff = x - mu;
    float var = diff * diff;
    #pragma unroll
    for (int m = 1; m <= 16; m <<= 1) var += __shfl_xor(var, m);
    var *= (1.0f / D);
    const float z1 = diff * rsqrtf(var + 1e-5f) * g1[c] + beta1[c];

    // FFN hidden
    const int j0 = lane, j1 = lane + 64;
    float h0 = b1[j0], h1 = b1[j1];
    #pragma unroll
    for (int k = 0; k < D; ++k) {
        const float zk = __shfl(z1, k);
        h0 += zk * W1[k * 128 + j0];
        h1 += zk * W1[k * 128 + j1];
    }
    h0 = fmaxf(h0, 0.f); h1 = fmaxf(h1, 0.f);

    float y = b2[c];
    #pragma unroll
    for (int jj = 0; jj < 64; ++jj) {
        y += __shfl(h0, jj) * W2[jj * D + c];
        y += __shfl(h1, jj) * W2[(jj + 64) * D + c];
    }

    const float x2 = z1 + y;
    float mu2 = x2;
    #pragma unroll
    for (int m = 1; m <= 16; m <<= 1) mu2 += __shfl_xor(mu2, m);
    mu2 *= (1.0f / D);
    const float d2 = x2 - mu2;
    float v2 = d2 * d2;
    #pragma unroll
    for (int m = 1; m <= 16; m <<= 1) v2 += __shfl_xor(v2, m);
    v2 *= (1.0f / D);
    const float res = d2 * rsqrtf(v2 + 1e-5f) * g2[c] + beta2[c];

    if (lane < 32) out[i * D + c] = res;
}

// ----------------------------------------------------------------
extern "C" void kernel_launch(void* const* d_in, const int* in_sizes, int n_in,
                              void* d_out, int out_size, void* d_ws, size_t ws_size,
                              hipStream_t stream) {
    const float* Z     = (const float*)d_in[0];
    const int*   mask  = (const int*)d_in[1];
    const float* Wq    = (const float*)d_in[2];
    const float* bq    = (const float*)d_in[3];
    const float* Wk    = (const float*)d_in[4];
    const float* bk    = (const float*)d_in[5];
    const float* Wv    = (const float*)d_in[6];
    const float* bv    = (const float*)d_in[7];
    const float* Wo    = (const float*)d_in[8];
    const float* bo    = (const float*)d_in[9];
    const float* W1    = (const float*)d_in[10];
    const float* b1    = (const float*)d_in[11];
    const float* W2    = (const float*)d_in[12];
    const float* b2    = (const float*)d_in[13];
    const float* g1    = (const float*)d_in[14];
    const float* be1   = (const float*)d_in[15];
    const float* g2    = (const float*)d_in[16];
    const float* be2   = (const float*)d_in[17];
    const float* omega = (const float*)d_in[18];
    float* out = (float*)d_out;

    float* Qw   = (float*)d_ws;           // N*D
    float* Kw   = Qw + N * D;             // N*D
    float* Vw   = Kw + N * D;             // N*D
    float* pQ   = Vw + N * D;             // N*R
    float* pK   = pQ + N * R;             // N*R
    float* kvw  = pK + N * R;             // R*D
    float* partw = kvw + R * D;           // JS*N*D

    hipMemsetAsync(kvw, 0, R * D * sizeof(float), stream);
    qkv_phi_kernel<<<N / 4, 128, 0, stream>>>(Z, Wq, bq, Wk, bk, Wv, bv, omega,
                                              Qw, Kw, Vw, pQ, pK);
    kv_kernel<<<N / 32, 256, 0, stream>>>(pK, Vw, kvw);
    attn_kernel<<<(N / TI) * JS, 256, 0, stream>>>(Qw, Kw, Vw, pQ, pK, mask, partw);
    epilogue_kernel<<<N / 4, 256, 0, stream>>>(partw, pQ, kvw, Z, Wo, bo,
                                               W1, b1, W2, b2, g1, be1, g2, be2, out);
}

// Round 3
// 167.800 us; speedup vs baseline: 2.3566x; 1.0469x over previous
//
#include <hip/hip_runtime.h>
#include <math.h>

#define N 2048
#define D 32
#define R 64
#define TI 8            // rows per attn block
#define JS 8            // j-splits
#define JT (N / JS)     // 256 j's per block

// (1/sqrt(d)) * log2(e), folded into stored Q
#define SCL (0.17677669529663687f * 1.4426950408889634f)
#define LOG2E 1.4426950408889634f

typedef float f2 __attribute__((ext_vector_type(2)));
typedef float f4 __attribute__((ext_vector_type(4)));

static __device__ __forceinline__ float fexp2(float x) {
    return __builtin_amdgcn_exp2f(x);
}

// ---------------------------------------------------------------- K1: QKV + phi (1 row/block)
// Layouts written:
//   Qs   [N][D]  row-major, pre-scaled by SCL
//   Kp   [D/2][N] of f2 (pair-transposed raw K)
//   Vg   [N][D]  row-major
//   phiQ [N][R]  row-major
//   phiKp[R/2][N] of f2 (pair-transposed phiK)
__global__ __launch_bounds__(128) void qkv_phi_kernel(
    const float* __restrict__ Z,
    const float* __restrict__ Wq, const float* __restrict__ bq,
    const float* __restrict__ Wk, const float* __restrict__ bk,
    const float* __restrict__ Wv, const float* __restrict__ bv,
    const float* __restrict__ omega,
    float* __restrict__ Qs, float* __restrict__ Kp, float* __restrict__ Vg,
    float* __restrict__ phiQ, float* __restrict__ phiKp)
{
    __shared__ float Qn[D], Kn[D];
    const int i = blockIdx.x;
    const int t = threadIdx.x;

    if (t < 96) {
        const int which = t >> 5;
        const int c = t & 31;
        const float* W = (which == 0) ? Wq : (which == 1) ? Wk : Wv;
        const float* b = (which == 0) ? bq : (which == 1) ? bk : bv;
        float acc = b[c];
        #pragma unroll
        for (int k = 0; k < D; ++k) acc += Z[i * D + k] * W[k * D + c];
        if (which == 0) {
            Qs[i * D + c] = acc * SCL;
            float ss = acc * acc;
            #pragma unroll
            for (int m = 1; m <= 16; m <<= 1) ss += __shfl_xor(ss, m);
            Qn[c] = acc / fmaxf(sqrtf(ss), 1e-6f);
        } else if (which == 1) {
            Kp[(c >> 1) * (2 * N) + i * 2 + (c & 1)] = acc;
            float ss = acc * acc;
            #pragma unroll
            for (int m = 1; m <= 16; m <<= 1) ss += __shfl_xor(ss, m);
            Kn[c] = acc / fmaxf(sqrtf(ss), 1e-6f);
        } else {
            Vg[i * D + c] = acc;
        }
    }
    __syncthreads();
    {
        const int r = t & 63;
        const float* src = (t < 64) ? Qn : Kn;
        float dot = 0.f;
        #pragma unroll
        for (int k = 0; k < D; ++k) dot += src[k] * omega[k * R + r];
        const float ph = fexp2(dot * LOG2E) * 0.125f;
        if (t < 64) phiQ[i * R + r] = ph;
        else        phiKp[(r >> 1) * (2 * N) + i * 2 + (r & 1)] = ph;
    }
}

// ---------------------------------------------------------------- K2: kv += phiK^T @ V (atomics)
__global__ __launch_bounds__(256) void kv_kernel(
    const float* __restrict__ phiKp, const float* __restrict__ Vg,
    float* __restrict__ kv)
{
    const int n0 = blockIdx.x * 8;
    const int t  = threadIdx.x;
    const int c  = t & 31;
    const int r0 = t >> 5;           // 0..7
    float acc[8];
    #pragma unroll
    for (int k = 0; k < 8; ++k) acc[k] = 0.f;
    #pragma unroll
    for (int n = n0; n < n0 + 8; ++n) {
        const float vv = Vg[n * D + c];
        #pragma unroll
        for (int k = 0; k < 8; ++k) {
            const int r = r0 + 8 * k;
            acc[k] += phiKp[(r >> 1) * (2 * N) + n * 2 + (r & 1)] * vv;
        }
    }
    #pragma unroll
    for (int k = 0; k < 8; ++k)
        atomicAdd(&kv[(r0 + 8 * k) * D + c], acc[k]);
}

// ---------------------------------------------------------------- K3: scores + S@V partials
__global__ __launch_bounds__(256, 6) void attn_kernel(
    const float* __restrict__ Qs, const float* __restrict__ Kp,
    const float* __restrict__ Vg, const float* __restrict__ phiQ,
    const float* __restrict__ phiKp, const int* __restrict__ mask,
    float* __restrict__ part)        // [JS][N][D]
{
    __shared__ float S[TI][JT];      // 8 KB
    __shared__ f4 red[4][64];        // 4 KB
    const int t    = threadIdx.x;
    const int rg   = blockIdx.x / JS;
    const int js   = blockIdx.x % JS;
    const int row0 = rg * TI;
    const int j    = js * JT + t;

    int mrow[TI];
    #pragma unroll
    for (int i = 0; i < TI; ++i) mrow[i] = mask[(size_t)(row0 + i) * N + j];

    f2 es[TI], pd[TI];
    #pragma unroll
    for (int i = 0; i < TI; ++i) { es[i] = (f2){0.f, 0.f}; pd[i] = (f2){0.f, 0.f}; }

    const f2* K2 = (const f2*)Kp;     // [16][N]
    const f2* P2 = (const f2*)phiKp;  // [32][N]

    #pragma unroll
    for (int p = 0; p < 16; ++p) {
        const f2 kk = K2[p * N + j];
        #pragma unroll
        for (int i = 0; i < TI; ++i) {
            const f2 q2 = *(const f2*)(Qs + (size_t)(row0 + i) * D + 2 * p); // uniform
            const f2 pr = kk * q2;
            es[i] += (f2){fexp2(pr.x), fexp2(pr.y)};
        }
    }
    #pragma unroll
    for (int p = 0; p < 32; ++p) {
        const f2 kk = P2[p * N + j];
        #pragma unroll
        for (int i = 0; i < TI; ++i) {
            const f2 q2 = *(const f2*)(phiQ + (size_t)(row0 + i) * R + 2 * p); // uniform
            pd[i] += kk * q2;
        }
    }
    #pragma unroll
    for (int i = 0; i < TI; ++i) {
        const float sc = (es[i].x + es[i].y) - (pd[i].x + pd[i].y);
        S[i][t] = (mrow[i] == 0) ? sc : 0.f;
    }
    __syncthreads();

    // phase 2: thread = (jg, ii, c4); V rows wave-uniform float4 reads
    const int jg = t >> 6;
    const int ii = (t >> 3) & 7;
    const int c4 = t & 7;
    f4 acc = {0.f, 0.f, 0.f, 0.f};
    const f4* V4 = (const f4*)(Vg + (size_t)js * JT * D);
    #pragma unroll 8
    for (int n = 0; n < 64; ++n) {
        const int jj = jg * 64 + n;
        const float s = S[ii][jj];
        acc += s * V4[jj * 8 + c4];
    }
    red[jg][t & 63] = acc;
    __syncthreads();
    if (t < 64) {
        const f4 rsum = (red[0][t] + red[1][t]) + (red[2][t] + red[3][t]);
        *(f4*)(part + ((size_t)js * N + row0 + (t >> 3)) * D + (t & 7) * 4) = rsum;
    }
}

// ---------------------------------------------------------------- K4: epilogue
__global__ __launch_bounds__(256) void epilogue_kernel(
    const float* __restrict__ part, const float* __restrict__ phiQ,
    const float* __restrict__ kv,   const float* __restrict__ Z,
    const float* __restrict__ Wo, const float* __restrict__ bo,
    const float* __restrict__ W1, const float* __restrict__ b1,
    const float* __restrict__ W2, const float* __restrict__ b2,
    const float* __restrict__ g1, const float* __restrict__ beta1,
    const float* __restrict__ g2, const float* __restrict__ beta2,
    float* __restrict__ out)
{
    const int i    = blockIdx.x * 4 + (threadIdx.x >> 6);
    const int lane = threadIdx.x & 63;
    const int c    = lane & 31;

    float a = 0.f;
    #pragma unroll
    for (int s = 0; s < JS; ++s) a += part[((size_t)s * N + i) * D + c];

    const float phi_r = phiQ[i * R + lane];
    float lr = 0.f;
    #pragma unroll
    for (int r = 0; r < R; ++r) lr += __shfl(phi_r, r) * kv[r * D + c];
    a += lr;

    float s = a;
    #pragma unroll
    for (int m = 1; m <= 16; m <<= 1) s += __shfl_xor(s, m);
    const float an = a / fmaxf(s, 1e-6f);

    float o = bo[c];
    #pragma unroll
    for (int k = 0; k < D; ++k) o += __shfl(an, k) * Wo[k * D + c];

    float x = Z[i * D + c] + o;
    float mu = x;
    #pragma unroll
    for (int m = 1; m <= 16; m <<= 1) mu += __shfl_xor(mu, m);
    mu *= (1.0f / D);
    const float diff = x - mu;
    float var = diff * diff;
    #pragma unroll
    for (int m = 1; m <= 16; m <<= 1) var += __shfl_xor(var, m);
    var *= (1.0f / D);
    const float z1 = diff * rsqrtf(var + 1e-5f) * g1[c] + beta1[c];

    const int j0 = lane, j1 = lane + 64;
    float h0 = b1[j0], h1 = b1[j1];
    #pragma unroll
    for (int k = 0; k < D; ++k) {
        const float zk = __shfl(z1, k);
        h0 += zk * W1[k * 128 + j0];
        h1 += zk * W1[k * 128 + j1];
    }
    h0 = fmaxf(h0, 0.f); h1 = fmaxf(h1, 0.f);

    float y = b2[c];
    #pragma unroll
    for (int jj = 0; jj < 64; ++jj) {
        y += __shfl(h0, jj) * W2[jj * D + c];
        y += __shfl(h1, jj) * W2[(jj + 64) * D + c];
    }

    const float x2 = z1 + y;
    float mu2 = x2;
    #pragma unroll
    for (int m = 1; m <= 16; m <<= 1) mu2 += __shfl_xor(mu2, m);
    mu2 *= (1.0f / D);
    const float d2 = x2 - mu2;
    float v2 = d2 * d2;
    #pragma unroll
    for (int m = 1; m <= 16; m <<= 1) v2 += __shfl_xor(v2, m);
    v2 *= (1.0f / D);
    const float res = d2 * rsqrtf(v2 + 1e-5f) * g2[c] + beta2[c];

    if (lane < 32) out[i * D + c] = res;
}

// ----------------------------------------------------------------
extern "C" void kernel_launch(void* const* d_in, const int* in_sizes, int n_in,
                              void* d_out, int out_size, void* d_ws, size_t ws_size,
                              hipStream_t stream) {
    const float* Z     = (const float*)d_in[0];
    const int*   mask  = (const int*)d_in[1];
    const float* Wq    = (const float*)d_in[2];
    const float* bq    = (const float*)d_in[3];
    const float* Wk    = (const float*)d_in[4];
    const float* bk    = (const float*)d_in[5];
    const float* Wv    = (const float*)d_in[6];
    const float* bv    = (const float*)d_in[7];
    const float* Wo    = (const float*)d_in[8];
    const float* bo    = (const float*)d_in[9];
    const float* W1    = (const float*)d_in[10];
    const float* b1    = (const float*)d_in[11];
    const float* W2    = (const float*)d_in[12];
    const float* b2    = (const float*)d_in[13];
    const float* g1    = (const float*)d_in[14];
    const float* be1   = (const float*)d_in[15];
    const float* g2    = (const float*)d_in[16];
    const float* be2   = (const float*)d_in[17];
    const float* omega = (const float*)d_in[18];
    float* out = (float*)d_out;

    float* Qsw   = (float*)d_ws;          // N*D
    float* Kpw   = Qsw + N * D;           // N*D
    float* Vw    = Kpw + N * D;           // N*D
    float* pQ    = Vw + N * D;            // N*R
    float* pKp   = pQ + N * R;            // N*R
    float* kvw   = pKp + N * R;           // R*D
    float* partw = kvw + R * D;           // JS*N*D

    hipMemsetAsync(kvw, 0, R * D * sizeof(float), stream);
    qkv_phi_kernel<<<N, 128, 0, stream>>>(Z, Wq, bq, Wk, bk, Wv, bv, omega,
                                          Qsw, Kpw, Vw, pQ, pKp);
    kv_kernel<<<N / 8, 256, 0, stream>>>(pKp, Vw, kvw);
    attn_kernel<<<(N / TI) * JS, 256, 0, stream>>>(Qsw, Kpw, Vw, pQ, pKp, mask, partw);
    epilogue_kernel<<<N / 4, 256, 0, stream>>>(partw, pQ, kvw, Z, Wo, bo,
                                               W1, b1, W2, b2, g1, be1, g2, be2, out);
}